// Round 13
// baseline (115.725 us; speedup 1.0000x reference)
//
#include <hip/hip_runtime.h>

// Problem constants (B=1)
#define R_   384
#define P_   (R_ * R_)      // 147456 pairs
#define NT_  4              // templates
#define CIN  128            // z channels
#define CKV  64             // t channels
#define NH   4              // heads
#define HC   256            // NH * 64

// Tiling
#define TP   64             // pairs per block (256 threads, 4 waves)
#define LDZ  136            // Z row stride (bf16) in s0z
#define LDA  280            // A/U row stride (bf16): 560B rows, 2-way banks max

typedef __attribute__((ext_vector_type(8))) short bf16x8;
typedef __attribute__((ext_vector_type(4))) float f32x4;
typedef __attribute__((ext_vector_type(4))) uint  u32x4;
typedef __attribute__((ext_vector_type(2))) __bf16 bfv2;

#if defined(__has_builtin)
#if __has_builtin(__builtin_amdgcn_fdot2_f32_bf16)
#define HAS_DOT2BF 1
#endif
#endif

// round-to-nearest-even f32 -> bf16 (bit-level, no HIP class types)
__device__ __forceinline__ ushort f2bf_s(float f) {
    uint32_t u = __float_as_uint(f);
    u += 0x7FFFu + ((u >> 16) & 1u);
    return (ushort)(u >> 16);
}
__device__ __forceinline__ uint packbf2(float lo, float hi) {
    return (uint)f2bf_s(lo) | ((uint)f2bf_s(hi) << 16);
}
__device__ __forceinline__ uint2 pack4(const float4 v) {
    uint2 r; r.x = packbf2(v.x, v.y); r.y = packbf2(v.z, v.w); return r;
}
__device__ __forceinline__ float bflo(uint t) { return __uint_as_float(t << 16); }
__device__ __forceinline__ float bfhi(uint t) { return __uint_as_float(t & 0xffff0000u); }

__device__ __forceinline__ float dot2bf(uint a, uint b, float acc) {
#ifdef HAS_DOT2BF
    union { uint u; bfv2 v; } ua, ub;
    ua.u = a; ub.u = b;
    return __builtin_amdgcn_fdot2_f32_bf16(ua.v, ub.v, acc, false);
#else
    float r = fmaf(bflo(a), bflo(b), acc);
    return fmaf(bfhi(a), bfhi(b), r);
#endif
}

// ---------------------------------------------------------------------------
// Precompute Mt[n][ci] = C^-0.5 * sum_c Wq[ci][h*64+c] * Wk[j][h*64+c]   (n = h*64+j)
//            Gt[co][n] =         sum_c Wv[j][h*64+c] * Wo[h*64+c][co]
// ---------------------------------------------------------------------------
__global__ __launch_bounds__(256) void precompute_mg(
        const float* __restrict__ Wq, const float* __restrict__ Wk,
        const float* __restrict__ Wv, const float* __restrict__ Wo,
        ushort* __restrict__ Mt, ushort* __restrict__ Gt) {
    int tid = blockIdx.x * blockDim.x + threadIdx.x;
    if (tid < HC * CIN) {
        int n = tid >> 7, ci = tid & 127;
        int h = n >> 6, j = n & 63;
        float acc = 0.f;
        for (int c = 0; c < 64; ++c)
            acc += Wq[ci * HC + h * 64 + c] * Wk[j * HC + h * 64 + c];
        Mt[n * CIN + ci] = f2bf_s(acc * 0.125f);   // C^-0.5 = 1/8
    } else {
        int t = tid - HC * CIN;
        int co = t >> 8, n = t & 255;
        int h = n >> 6, j = n & 63;
        float acc = 0.f;
        for (int c = 0; c < 64; ++c)
            acc += Wv[j * HC + h * 64 + c] * Wo[(h * 64 + c) * CIN + co];
        Gt[co * HC + n] = f2bf_s(acc);
    }
}

// ---------------------------------------------------------------------------
// Fused kernel: T never touches LDS (lives in 32 VGPR per thread).
//   thread role for middle: p = wv*16 + (lane&15), q = lane>>4 (c-quarter).
//   [Z->LDS, T->regs] bar1 [GEMM1 swapped, B1 in 2 halves] [packed b64 spill]
//   bar2 [B2 loads ; middle: A-read(8 b128), logits (dot2), shfl_xor q-reduce,
//   softmax (w in regs), U from T-regs -> LDS (8 b128)] bar3 [GEMM2 ; store].
//   LDS = 53.2 KB -> 3 blocks/CU; 3 barriers.
// ---------------------------------------------------------------------------
__global__ __launch_bounds__(256, 3) void tpa_fused(
        const float* __restrict__ z2d, const float* __restrict__ t2d,
        const ushort* __restrict__ Mt, const ushort* __restrict__ Gt,
        const float* __restrict__ bo, float* __restrict__ out) {

    __shared__ ushort s0z[TP * LDZ];   // Z bf16: 17408 B
    __shared__ ushort s0a[TP * LDA];   // A then U bf16: 35840 B

    const int tid  = threadIdx.x;
    const int lane = tid & 63;
    const int wv   = tid >> 6;           // wave
    const int lr   = lane & 15;
    const int g    = lane >> 4;          // 0..3 (= c-quarter q in middle)
    const int g8   = g << 3;
    const int pg0  = blockIdx.x * TP;
    const int pm   = wv * 16 + lr;       // middle row owned by this thread

    // ---- T loads -> packed bf16 regs (32 VGPR), consumed in middle -------
    // thread needs T[pm, k*64 + g*16 .. +16) : one 64B line per (k)
    u32x4 tb[NT_][2];
    #pragma unroll
    for (int k = 0; k < NT_; ++k) {
        const float* tp = t2d + ((size_t)k * P_ + pg0 + pm) * CKV + g * 16;
        float4 ta = *(const float4*)(tp);
        float4 tb4 = *(const float4*)(tp + 4);
        float4 tc = *(const float4*)(tp + 8);
        float4 td = *(const float4*)(tp + 12);
        tb[k][0][0] = packbf2(ta.x, ta.y); tb[k][0][1] = packbf2(ta.z, ta.w);
        tb[k][0][2] = packbf2(tb4.x, tb4.y); tb[k][0][3] = packbf2(tb4.z, tb4.w);
        tb[k][1][0] = packbf2(tc.x, tc.y); tb[k][1][1] = packbf2(tc.z, tc.w);
        tb[k][1][2] = packbf2(td.x, td.y); tb[k][1][3] = packbf2(td.z, td.w);
    }

    // ---- stage Z -> LDS bf16 (coalesced) ----------------------------------
    #pragma unroll
    for (int i = 0; i < 8; ++i) {
        int idx = (i * 256 + tid) * 4, p = idx >> 7, c = idx & 127;
        float4 v = *(const float4*)(z2d + (size_t)(pg0 + p) * CIN + c);
        *(uint2*)&s0z[p * LDZ + c] = pack4(v);
    }
    __syncthreads();   // bar1: Z staged

    // ---- GEMM1 (swapped): acc1[nt][mt] = (M'^T tile) x (Z^T tile) ---------
    //      D[row = n-in-16][col = p-in-16]; n = wv*64+nt*16+g*4+r, p = mt*16+lr
    //      B1 loaded in 2 kt-halves to cap VGPR.
    f32x4 acc1[4][4];
    #pragma unroll
    for (int nt = 0; nt < 4; ++nt)
        #pragma unroll
        for (int mt = 0; mt < 4; ++mt)
            acc1[nt][mt] = (f32x4){0.f, 0.f, 0.f, 0.f};

    #pragma unroll
    for (int half = 0; half < 2; ++half) {
        bf16x8 B1[2][4];
        #pragma unroll
        for (int kt2 = 0; kt2 < 2; ++kt2)
            #pragma unroll
            for (int nt = 0; nt < 4; ++nt)
                B1[kt2][nt] = *(const bf16x8*)(Mt + (wv * 64 + nt * 16 + lr) * CIN
                                               + (half * 2 + kt2) * 32 + g8);
        #pragma unroll
        for (int kt2 = 0; kt2 < 2; ++kt2) {
            int kt = half * 2 + kt2;
            bf16x8 zf[4];
            #pragma unroll
            for (int mt = 0; mt < 4; ++mt)
                zf[mt] = *(const bf16x8*)&s0z[(mt * 16 + lr) * LDZ + kt * 32 + g8];
            #pragma unroll
            for (int nt = 0; nt < 4; ++nt)
                #pragma unroll
                for (int mt = 0; mt < 4; ++mt)
                    acc1[nt][mt] = __builtin_amdgcn_mfma_f32_16x16x32_bf16(
                        B1[kt2][nt], zf[mt], acc1[nt][mt], 0, 0, 0);
        }
    }

    // ---- spill A^T -> s0a[p][n] packed b64 (4 consecutive n) --------------
    #pragma unroll
    for (int nt = 0; nt < 4; ++nt) {
        int n0 = wv * 64 + nt * 16 + g * 4;
        #pragma unroll
        for (int mt = 0; mt < 4; ++mt) {
            int p = mt * 16 + lr;
            uint2 w;
            w.x = packbf2(acc1[nt][mt][0], acc1[nt][mt][1]);
            w.y = packbf2(acc1[nt][mt][2], acc1[nt][mt][3]);
            *(uint2*)&s0a[p * LDA + n0] = w;
        }
    }
    __syncthreads();   // bar2: all spills visible (middle reads cross-wave cols)

    // ---- B2 + bias loads: L2 latency hides under middle -------------------
    bf16x8 B2[8][2];   // [kt][nt], wave wv -> out cols [wv*32, +32)
    #pragma unroll
    for (int kt = 0; kt < 8; ++kt)
        #pragma unroll
        for (int nt = 0; nt < 2; ++nt)
            B2[kt][nt] = *(const bf16x8*)(Gt + (wv * 32 + nt * 16 + lr) * HC + kt * 32 + g8);
    const float bias0 = bo[wv * 32 + lr];
    const float bias1 = bo[wv * 32 + 16 + lr];

    // ---- middle: thread (pm, q=g): logits over own c-quarter, q-reduce ----
    {
        u32x4 a2[4][2];                      // A[pm, h*64 + g*16 .. +16), 4 h
        #pragma unroll
        for (int h = 0; h < 4; ++h) {
            a2[h][0] = *(const u32x4*)&s0a[pm * LDA + h * 64 + g * 16];
            a2[h][1] = *(const u32x4*)&s0a[pm * LDA + h * 64 + g * 16 + 8];
        }

        float lg[4][4];
        #pragma unroll
        for (int h = 0; h < 4; ++h)
            #pragma unroll
            for (int k = 0; k < NT_; ++k) {
                float s = 0.f;
                #pragma unroll
                for (int j = 0; j < 2; ++j)
                    #pragma unroll
                    for (int e = 0; e < 4; ++e)
                        s = dot2bf(a2[h][j][e], tb[k][j][e], s);
                lg[h][k] = s;
            }
        // reduce partial logits across the 4 q-lanes (butterfly)
        #pragma unroll
        for (int h = 0; h < 4; ++h)
            #pragma unroll
            for (int k = 0; k < NT_; ++k) {
                float s = lg[h][k];
                s += __shfl_xor(s, 16);
                s += __shfl_xor(s, 32);
                lg[h][k] = s;
            }
        // softmax per h (all q-lanes redundantly); weights stay in registers
        float wgt[4][4];
        #pragma unroll
        for (int h = 0; h < 4; ++h) {
            float mx = fmaxf(fmaxf(lg[h][0], lg[h][1]), fmaxf(lg[h][2], lg[h][3]));
            float e0 = __expf(lg[h][0] - mx), e1 = __expf(lg[h][1] - mx);
            float e2 = __expf(lg[h][2] - mx), e3 = __expf(lg[h][3] - mx);
            float inv = 1.f / (e0 + e1 + e2 + e3);
            wgt[h][0] = e0 * inv; wgt[h][1] = e1 * inv;
            wgt[h][2] = e2 * inv; wgt[h][3] = e3 * inv;
        }
        // U[pm, h*64 + g*16 .. +16) from T-regs; overwrite own A slice
        #pragma unroll
        for (int h = 0; h < 4; ++h) {
            #pragma unroll
            for (int j = 0; j < 2; ++j) {
                u32x4 o;
                #pragma unroll
                for (int e = 0; e < 4; ++e) {
                    uint t0 = tb[0][j][e], t1 = tb[1][j][e];
                    uint t2 = tb[2][j][e], t3 = tb[3][j][e];
                    float lo = wgt[h][0] * bflo(t0) + wgt[h][1] * bflo(t1)
                             + wgt[h][2] * bflo(t2) + wgt[h][3] * bflo(t3);
                    float hi = wgt[h][0] * bfhi(t0) + wgt[h][1] * bfhi(t1)
                             + wgt[h][2] * bfhi(t2) + wgt[h][3] * bfhi(t3);
                    o[e] = packbf2(lo, hi);
                }
                *(u32x4*)&s0a[pm * LDA + h * 64 + g * 16 + j * 8] = o;
            }
        }
    }
    __syncthreads();   // bar3: U visible to all waves

    // ---- GEMM2: OUT[64][128] = U[64][256] @ G ------------------------------
    f32x4 acc2[4][2];
    #pragma unroll
    for (int mt = 0; mt < 4; ++mt)
        #pragma unroll
        for (int nt = 0; nt < 2; ++nt)
            acc2[mt][nt] = (f32x4){0.f, 0.f, 0.f, 0.f};
    #pragma unroll
    for (int kt = 0; kt < 8; ++kt) {
        bf16x8 af[4];
        #pragma unroll
        for (int mt = 0; mt < 4; ++mt)
            af[mt] = *(const bf16x8*)&s0a[(mt * 16 + lr) * LDA + kt * 32 + g8];
        #pragma unroll
        for (int mt = 0; mt < 4; ++mt)
            #pragma unroll
            for (int nt = 0; nt < 2; ++nt)
                acc2[mt][nt] = __builtin_amdgcn_mfma_f32_16x16x32_bf16(
                    af[mt], B2[kt][nt], acc2[mt][nt], 0, 0, 0);
    }

    // ---- epilogue: bias + fp32 store ---------------------------------------
    #pragma unroll
    for (int nt = 0; nt < 2; ++nt) {
        int co = wv * 32 + nt * 16 + lr;
        float bias = nt ? bias1 : bias0;
        #pragma unroll
        for (int mt = 0; mt < 4; ++mt) {
            int row = mt * 16 + g * 4;
            #pragma unroll
            for (int r = 0; r < 4; ++r)
                out[(size_t)(pg0 + row + r) * CIN + co] = acc2[mt][nt][r] + bias;
        }
    }
}

extern "C" void kernel_launch(void* const* d_in, const int* in_sizes, int n_in,
                              void* d_out, int out_size, void* d_ws, size_t ws_size,
                              hipStream_t stream) {
    const float* z2d = (const float*)d_in[0];
    const float* t2d = (const float*)d_in[1];
    const float* Wq  = (const float*)d_in[2];
    const float* Wk  = (const float*)d_in[3];
    const float* Wv  = (const float*)d_in[4];
    const float* Wo  = (const float*)d_in[5];
    const float* bo  = (const float*)d_in[6];

    ushort* Mt = (ushort*)d_ws;            // 256x128 bf16
    ushort* Gt = Mt + HC * CIN;            // 128x256 bf16

    precompute_mg<<<(2 * HC * CIN) / 256, 256, 0, stream>>>(Wq, Wk, Wv, Wo, Mt, Gt);
    tpa_fused<<<P_ / TP, 256, 0, stream>>>(z2d, t2d, Mt, Gt, bo, (float*)d_out);
}